// Round 1
// baseline (3215.873 us; speedup 1.0000x reference)
//
#include <hip/hip_runtime.h>
#include <hip/hip_bf16.h>
#include <math.h>

namespace {

constexpr int kB = 128, kF = 2048, kH = 1024, kE = 512, kV = 16384, kT = 20;

typedef __attribute__((ext_vector_type(4))) float f32x4;
typedef __attribute__((ext_vector_type(8))) short bf16x8;

#define MFMA(a, b, c) __builtin_amdgcn_mfma_f32_16x16x32_bf16((a), (b), (c), 0, 0, 0)

__device__ __forceinline__ short f2bf(float f) {
  union { float f; unsigned u; } un;
  un.f = f;
  unsigned x = un.u;
  x += 0x7fffu + ((x >> 16) & 1u);
  return (short)(x >> 16);
}

__device__ __forceinline__ float sigm(float x) { return 1.0f / (1.0f + __expf(-x)); }

__device__ __forceinline__ void cvt4(const float* __restrict__ s, short* __restrict__ d,
                                     long n4, long gid, long gs) {
  for (long i = gid; i < n4; i += gs) {
    float4 v = ((const float4*)s)[i];
    short4 o;
    o.x = f2bf(v.x); o.y = f2bf(v.y); o.z = f2bf(v.z); o.w = f2bf(v.w);
    ((short4*)d)[i] = o;
  }
}

// ---------------- prologue: fp32 -> bf16 weight conversion + e0 ----------------
__global__ __launch_bounds__(256) void k_convert(
    const float* __restrict__ wout, const float* __restrict__ emb,
    const float* __restrict__ wih, const float* __restrict__ whh,
    const float* __restrict__ aw, const float* __restrict__ img,
    const float* __restrict__ sos,
    short* __restrict__ wout_b, short* __restrict__ emb_b,
    short* __restrict__ wih_b, short* __restrict__ whh_b,
    short* __restrict__ aw_b, short* __restrict__ img_b,
    short* __restrict__ e0_b) {
  long gid = (long)blockIdx.x * blockDim.x + threadIdx.x;
  long gs = (long)gridDim.x * blockDim.x;
  cvt4(wout, wout_b, (long)kV * kH / 4, gid, gs);
  cvt4(emb, emb_b, (long)kE * kV / 4, gid, gs);
  cvt4(wih, wih_b, (long)3 * kH * kE / 4, gid, gs);
  cvt4(whh, whh_b, (long)3 * kH * kH / 4, gid, gs);
  cvt4(aw, aw_b, (long)kH * kF / 4, gid, gs);
  cvt4(img, img_b, (long)kB * kF / 4, gid, gs);
  for (long i = gid; i < kB * kE; i += gs) e0_b[i] = f2bf(sos[i & (kE - 1)]);
}

// ---------------- h0 = img @ agent_w.T + agent_b ----------------
// grid 64 (H/16 col tiles), 256 thr (4 waves, wave w = rows 32w..32w+31)
__global__ __launch_bounds__(256) void k_h0(const short* __restrict__ img_b,
                                            const short* __restrict__ aw_b,
                                            const float* __restrict__ ab,
                                            float* __restrict__ hf, short* __restrict__ hb) {
  int tid = threadIdx.x;
  int l = tid & 63, w = tid >> 6;
  int lr = l & 15, g = l >> 4, lk = g * 8;
  int col0 = blockIdx.x * 16;
  int row0 = w * 32;
  f32x4 acc[2] = {};
#pragma unroll 4
  for (int k0 = 0; k0 < kF; k0 += 32) {
    bf16x8 a0 = *(const bf16x8*)&img_b[(row0 + lr) * kF + k0 + lk];
    bf16x8 a1 = *(const bf16x8*)&img_b[(row0 + 16 + lr) * kF + k0 + lk];
    bf16x8 b = *(const bf16x8*)&aw_b[(size_t)(col0 + lr) * kF + k0 + lk];
    acc[0] = MFMA(a0, b, acc[0]);
    acc[1] = MFMA(a1, b, acc[1]);
  }
  int col = col0 + lr;
  float bias = ab[col];
#pragma unroll
  for (int mf = 0; mf < 2; ++mf)
#pragma unroll
    for (int j = 0; j < 4; ++j) {
      int row = row0 + mf * 16 + g * 4 + j;
      float v = acc[mf][j] + bias;
      hf[row * kH + col] = v;
      hb[row * kH + col] = f2bf(v);
    }
}

// ---------------- GRU cell ----------------
// grid 64 (H/16 col tiles), 256 thr; wave w = rows 32w..32w+31
__global__ __launch_bounds__(256) void k_gru(
    const short* __restrict__ e_b, const short* __restrict__ hb_prev,
    const float* __restrict__ hf_prev,
    const short* __restrict__ wih_b, const short* __restrict__ whh_b,
    const float* __restrict__ bih, const float* __restrict__ bhh,
    float* __restrict__ hf_next, short* __restrict__ hb_next) {
  int tid = threadIdx.x;
  int l = tid & 63, w = tid >> 6;
  int lr = l & 15, g = l >> 4, lk = g * 8;
  int col0 = blockIdx.x * 16;
  int row0 = w * 32;
  f32x4 air[2] = {}, aiz[2] = {}, ain[2] = {};
  f32x4 ahr[2] = {}, ahz[2] = {}, ahn[2] = {};
#pragma unroll 2
  for (int k0 = 0; k0 < kE; k0 += 32) {
    bf16x8 a0 = *(const bf16x8*)&e_b[(row0 + lr) * kE + k0 + lk];
    bf16x8 a1 = *(const bf16x8*)&e_b[(row0 + 16 + lr) * kE + k0 + lk];
    bf16x8 br = *(const bf16x8*)&wih_b[(size_t)(col0 + lr) * kE + k0 + lk];
    bf16x8 bz = *(const bf16x8*)&wih_b[(size_t)(kH + col0 + lr) * kE + k0 + lk];
    bf16x8 bn = *(const bf16x8*)&wih_b[(size_t)(2 * kH + col0 + lr) * kE + k0 + lk];
    air[0] = MFMA(a0, br, air[0]); air[1] = MFMA(a1, br, air[1]);
    aiz[0] = MFMA(a0, bz, aiz[0]); aiz[1] = MFMA(a1, bz, aiz[1]);
    ain[0] = MFMA(a0, bn, ain[0]); ain[1] = MFMA(a1, bn, ain[1]);
  }
#pragma unroll 2
  for (int k0 = 0; k0 < kH; k0 += 32) {
    bf16x8 a0 = *(const bf16x8*)&hb_prev[(row0 + lr) * kH + k0 + lk];
    bf16x8 a1 = *(const bf16x8*)&hb_prev[(row0 + 16 + lr) * kH + k0 + lk];
    bf16x8 br = *(const bf16x8*)&whh_b[(size_t)(col0 + lr) * kH + k0 + lk];
    bf16x8 bz = *(const bf16x8*)&whh_b[(size_t)(kH + col0 + lr) * kH + k0 + lk];
    bf16x8 bn = *(const bf16x8*)&whh_b[(size_t)(2 * kH + col0 + lr) * kH + k0 + lk];
    ahr[0] = MFMA(a0, br, ahr[0]); ahr[1] = MFMA(a1, br, ahr[1]);
    ahz[0] = MFMA(a0, bz, ahz[0]); ahz[1] = MFMA(a1, bz, ahz[1]);
    ahn[0] = MFMA(a0, bn, ahn[0]); ahn[1] = MFMA(a1, bn, ahn[1]);
  }
  int col = col0 + lr;
  float bihr = bih[col], bhhr = bhh[col];
  float bihz = bih[kH + col], bhhz = bhh[kH + col];
  float bihn = bih[2 * kH + col], bhhn = bhh[2 * kH + col];
#pragma unroll
  for (int mf = 0; mf < 2; ++mf)
#pragma unroll
    for (int j = 0; j < 4; ++j) {
      int row = row0 + mf * 16 + g * 4 + j;
      float r = sigm(air[mf][j] + ahr[mf][j] + bihr + bhhr);
      float z = sigm(aiz[mf][j] + ahz[mf][j] + bihz + bhhz);
      float nn = tanhf(ain[mf][j] + bihn + r * (ahn[mf][j] + bhhn));
      float hv = (1.0f - z) * nn + z * hf_prev[row * kH + col];
      hf_next[row * kH + col] = hv;
      hb_next[row * kH + col] = f2bf(hv);
    }
}

// ---------------- logits GEMM + per-block softmax stats ----------------
// grid 256 (V/64 col tiles), 256 thr; waves 2x2: wave covers 64 rows x 32 cols
__global__ __launch_bounds__(256) void k_logits(
    const short* __restrict__ h_b, const short* __restrict__ wout_b,
    const float* __restrict__ bout, const float* __restrict__ gum_t,
    float* __restrict__ logits, float* __restrict__ smax, float* __restrict__ ssum) {
  int tid = threadIdx.x;
  int l = tid & 63, w = tid >> 6;
  int lr = l & 15, g = l >> 4, lk = g * 8;
  int n0 = blockIdx.x * 64;
  int mrow0 = (w >> 1) * 64;
  int nc0 = n0 + (w & 1) * 32;
  f32x4 acc[4][2] = {};
#pragma unroll 2
  for (int k0 = 0; k0 < kH; k0 += 32) {
    bf16x8 a[4], b[2];
#pragma unroll
    for (int mf = 0; mf < 4; ++mf)
      a[mf] = *(const bf16x8*)&h_b[(mrow0 + mf * 16 + lr) * kH + k0 + lk];
#pragma unroll
    for (int nf = 0; nf < 2; ++nf)
      b[nf] = *(const bf16x8*)&wout_b[(size_t)(nc0 + nf * 16 + lr) * kH + k0 + lk];
#pragma unroll
    for (int mf = 0; mf < 4; ++mf)
#pragma unroll
      for (int nf = 0; nf < 2; ++nf) acc[mf][nf] = MFMA(a[mf], b[nf], acc[mf][nf]);
  }
  __shared__ float wmax[4][64];
  __shared__ float wsum[4][64];
  float bo0 = bout[nc0 + lr], bo1 = bout[nc0 + 16 + lr];
#pragma unroll
  for (int mf = 0; mf < 4; ++mf)
#pragma unroll
    for (int j = 0; j < 4; ++j) {
      int row = mrow0 + mf * 16 + g * 4 + j;
      float v0 = acc[mf][0][j] + bo0 + gum_t[(size_t)row * kV + nc0 + lr];
      float v1 = acc[mf][1][j] + bo1 + gum_t[(size_t)row * kV + nc0 + 16 + lr];
      logits[(size_t)row * kV + nc0 + lr] = v0;
      logits[(size_t)row * kV + nc0 + 16 + lr] = v1;
      acc[mf][0][j] = v0;
      acc[mf][1][j] = v1;
      float m = fmaxf(v0, v1);
#pragma unroll
      for (int s = 1; s < 16; s <<= 1) m = fmaxf(m, __shfl_xor(m, s, 64));
      if (lr == 0) wmax[w][mf * 16 + g * 4 + j] = m;
    }
  __syncthreads();
#pragma unroll
  for (int mf = 0; mf < 4; ++mf)
#pragma unroll
    for (int j = 0; j < 4; ++j) {
      int rl = mf * 16 + g * 4 + j;
      float bm = fmaxf(wmax[w][rl], wmax[w ^ 1][rl]);
      float s = __expf(acc[mf][0][j] - bm) + __expf(acc[mf][1][j] - bm);
#pragma unroll
      for (int sf = 1; sf < 16; sf <<= 1) s += __shfl_xor(s, sf, 64);
      if (lr == 0) wsum[w][rl] = s;
    }
  __syncthreads();
  if (tid < 128) {
    int row = tid;
    int hh = row >> 6, rl = row & 63;
    float m = fmaxf(wmax[2 * hh][rl], wmax[2 * hh + 1][rl]);
    float s = wsum[2 * hh][rl] + wsum[2 * hh + 1][rl];
    smax[(size_t)row * 256 + blockIdx.x] = m;
    ssum[(size_t)row * 256 + blockIdx.x] = s;
  }
}

// ---------------- x = softmax, write out, e-partials = x @ emb.T ----------------
// grid 64 = (kc 16 V-chunks of 1024) x (et 4 E-tiles of 128); 256 thr
__global__ __launch_bounds__(256) void k_xe(
    const float* __restrict__ logits, const float* __restrict__ smax,
    const float* __restrict__ ssum, const short* __restrict__ emb_b,
    float* __restrict__ outp, float* __restrict__ epart) {
  int tid = threadIdx.x;
  int et = blockIdx.x & 3;
  int kc = blockIdx.x >> 2;
  __shared__ float s_m[kB], s_rd[kB];
  __shared__ float tmp2[kB][2];
  {
    int row = tid >> 1, h = tid & 1;
    const float* mrow = smax + (size_t)row * 256;
    const float* srow = ssum + (size_t)row * 256;
    float mloc = -3.0e38f;
    for (int b = h * 128; b < h * 128 + 128; ++b) mloc = fmaxf(mloc, mrow[b]);
    tmp2[row][h] = mloc;
    __syncthreads();
    float m = fmaxf(tmp2[row][0], tmp2[row][1]);
    float dloc = 0.0f;
    for (int b = h * 128; b < h * 128 + 128; ++b) dloc += srow[b] * __expf(mrow[b] - m);
    __syncthreads();
    tmp2[row][h] = dloc;
    __syncthreads();
    if (h == 0) {
      s_m[row] = m;
      s_rd[row] = 1.0f / (tmp2[row][0] + tmp2[row][1]);
    }
    __syncthreads();
  }
  __shared__ short xs[kB][136];
  int l = tid & 63, w = tid >> 6;
  int lr = l & 15, g = l >> 4, lk = g * 8;
  int mrow0 = (w >> 1) * 64;
  int ec0 = et * 128 + (w & 1) * 64;
  int vc0 = kc * 1024;
  f32x4 acc[4][4] = {};
  for (int ss = 0; ss < 8; ++ss) {
    int c0 = vc0 + ss * 128;
    // stage x (fp32 out + bf16 LDS)
#pragma unroll 4
    for (int i = 0; i < 16; ++i) {
      int id = tid + i * 256;       // 0..4095 float4s
      int row = id >> 5;
      int c4 = (id & 31) << 2;
      float4 lv = *(const float4*)&logits[(size_t)row * kV + c0 + c4];
      float m = s_m[row], rd = s_rd[row];
      float x0 = __expf(lv.x - m) * rd;
      float x1 = __expf(lv.y - m) * rd;
      float x2 = __expf(lv.z - m) * rd;
      float x3 = __expf(lv.w - m) * rd;
      if (et == 0) {
        float4 ov; ov.x = x0; ov.y = x1; ov.z = x2; ov.w = x3;
        *(float4*)&outp[(size_t)row * (kT * kV) + c0 + c4] = ov;
      }
      short4 xb;
      xb.x = f2bf(x0); xb.y = f2bf(x1); xb.z = f2bf(x2); xb.w = f2bf(x3);
      *(short4*)&xs[row][c4] = xb;
    }
    __syncthreads();
#pragma unroll
    for (int kk = 0; kk < 128; kk += 32) {
      bf16x8 a[4], b[4];
#pragma unroll
      for (int mf = 0; mf < 4; ++mf)
        a[mf] = *(const bf16x8*)&xs[mrow0 + mf * 16 + lr][kk + lk];
#pragma unroll
      for (int nf = 0; nf < 4; ++nf)
        b[nf] = *(const bf16x8*)&emb_b[(size_t)(ec0 + nf * 16 + lr) * kV + c0 + kk + lk];
#pragma unroll
      for (int mf = 0; mf < 4; ++mf)
#pragma unroll
        for (int nf = 0; nf < 4; ++nf) acc[mf][nf] = MFMA(a[mf], b[nf], acc[mf][nf]);
    }
    __syncthreads();
  }
#pragma unroll
  for (int mf = 0; mf < 4; ++mf)
#pragma unroll
    for (int nf = 0; nf < 4; ++nf)
#pragma unroll
      for (int j = 0; j < 4; ++j) {
        int row = mrow0 + mf * 16 + g * 4 + j;
        int col = ec0 + nf * 16 + lr;
        epart[((size_t)kc * kB + row) * kE + col] = acc[mf][nf][j];
      }
}

// ---------------- e = sum of partials -> bf16 ----------------
__global__ __launch_bounds__(256) void k_ereduce(const float* __restrict__ epart,
                                                 short* __restrict__ e_b) {
  int idx = blockIdx.x * blockDim.x + threadIdx.x;   // 8192 threads
  for (int i = idx; i < kB * kE; i += 8192) {
    float s = 0.0f;
#pragma unroll
    for (int k = 0; k < 16; ++k) s += epart[(size_t)k * kB * kE + i];
    e_b[i] = f2bf(s);
  }
}

}  // namespace

extern "C" void kernel_launch(void* const* d_in, const int* in_sizes, int n_in,
                              void* d_out, int out_size, void* d_ws, size_t ws_size,
                              hipStream_t stream) {
  const float* img = (const float*)d_in[0];
  const float* aw = (const float*)d_in[1];
  const float* ab = (const float*)d_in[2];
  const float* wih = (const float*)d_in[3];
  const float* whh = (const float*)d_in[4];
  const float* bih = (const float*)d_in[5];
  const float* bhh = (const float*)d_in[6];
  const float* wout = (const float*)d_in[7];
  const float* bout = (const float*)d_in[8];
  const float* emb = (const float*)d_in[9];
  const float* sos = (const float*)d_in[10];
  const float* gum = (const float*)d_in[11];
  float* out = (float*)d_out;
  char* ws = (char*)d_ws;

  short* wout_b = (short*)(ws + 0);            // 33554432
  short* emb_b = (short*)(ws + 33554432);      // 16777216
  short* wih_b = (short*)(ws + 50331648);      // 3145728
  short* whh_b = (short*)(ws + 53477376);      // 6291456
  short* aw_b = (short*)(ws + 59768832);       // 4194304
  short* img_b = (short*)(ws + 63963136);      // 524288
  float* hf0 = (float*)(ws + 64487424);        // 524288
  float* hf1 = (float*)(ws + 65011712);        // 524288
  short* hb0 = (short*)(ws + 65536000);        // 262144
  short* hb1 = (short*)(ws + 65798144);        // 262144
  short* e_b = (short*)(ws + 66060288);        // 131072
  float* logits = (float*)(ws + 66191360);     // 8388608
  float* smax = (float*)(ws + 74579968);       // 131072
  float* ssum = (float*)(ws + 74711040);       // 131072
  float* epart = (float*)(ws + 74842112);      // 4194304

  float* hf[2] = {hf0, hf1};
  short* hb[2] = {hb0, hb1};

  k_convert<<<2048, 256, 0, stream>>>(wout, emb, wih, whh, aw, img, sos, wout_b, emb_b,
                                      wih_b, whh_b, aw_b, img_b, e_b);
  k_h0<<<64, 256, 0, stream>>>(img_b, aw_b, ab, hf[0], hb[0]);
  for (int t = 0; t < kT; ++t) {
    int rp = t & 1, wp = rp ^ 1;
    k_gru<<<64, 256, 0, stream>>>(e_b, hb[rp], hf[rp], wih_b, whh_b, bih, bhh, hf[wp],
                                  hb[wp]);
    k_logits<<<256, 256, 0, stream>>>(hb[wp], wout_b, bout, gum + (size_t)t * kB * kV,
                                      logits, smax, ssum);
    k_xe<<<64, 256, 0, stream>>>(logits, smax, ssum, emb_b, out + (size_t)t * kV, epart);
    k_ereduce<<<32, 256, 0, stream>>>(epart, e_b);
  }
}

// Round 2
// 3064.229 us; speedup vs baseline: 1.0495x; 1.0495x over previous
//
#include <hip/hip_runtime.h>
#include <hip/hip_bf16.h>
#include <math.h>

namespace {

constexpr int kB = 128, kF = 2048, kH = 1024, kE = 512, kV = 16384, kT = 20;

typedef __attribute__((ext_vector_type(4))) float f32x4;
typedef __attribute__((ext_vector_type(8))) short bf16x8;

#define MFMA(a, b, c) __builtin_amdgcn_mfma_f32_16x16x32_bf16((a), (b), (c), 0, 0, 0)

__device__ __forceinline__ short f2bf(float f) {
  union { float f; unsigned u; } un;
  un.f = f;
  unsigned x = un.u;
  x += 0x7fffu + ((x >> 16) & 1u);
  return (short)(x >> 16);
}

__device__ __forceinline__ float sigm(float x) { return 1.0f / (1.0f + __expf(-x)); }

__device__ __forceinline__ void cvt4(const float* __restrict__ s, short* __restrict__ d,
                                     long n4, long gid, long gs) {
  for (long i = gid; i < n4; i += gs) {
    float4 v = ((const float4*)s)[i];
    short4 o;
    o.x = f2bf(v.x); o.y = f2bf(v.y); o.z = f2bf(v.z); o.w = f2bf(v.w);
    ((short4*)d)[i] = o;
  }
}

// ---------------- prologue: fp32 -> bf16 weight conversion + e0 ----------------
__global__ __launch_bounds__(256) void k_convert(
    const float* __restrict__ wout, const float* __restrict__ emb,
    const float* __restrict__ wih, const float* __restrict__ whh,
    const float* __restrict__ aw, const float* __restrict__ img,
    const float* __restrict__ sos,
    short* __restrict__ wout_b, short* __restrict__ emb_b,
    short* __restrict__ wih_b, short* __restrict__ whh_b,
    short* __restrict__ aw_b, short* __restrict__ img_b,
    short* __restrict__ e0_b) {
  long gid = (long)blockIdx.x * blockDim.x + threadIdx.x;
  long gs = (long)gridDim.x * blockDim.x;
  cvt4(wout, wout_b, (long)kV * kH / 4, gid, gs);
  cvt4(emb, emb_b, (long)kE * kV / 4, gid, gs);
  cvt4(wih, wih_b, (long)3 * kH * kE / 4, gid, gs);
  cvt4(whh, whh_b, (long)3 * kH * kH / 4, gid, gs);
  cvt4(aw, aw_b, (long)kH * kF / 4, gid, gs);
  cvt4(img, img_b, (long)kB * kF / 4, gid, gs);
  for (long i = gid; i < kB * kE; i += gs) e0_b[i] = f2bf(sos[i & (kE - 1)]);
}

// ---------------- h0 = img @ agent_w.T + agent_b ----------------
__global__ __launch_bounds__(256) void k_h0(const short* __restrict__ img_b,
                                            const short* __restrict__ aw_b,
                                            const float* __restrict__ ab,
                                            float* __restrict__ hf, short* __restrict__ hb) {
  int tid = threadIdx.x;
  int l = tid & 63, w = tid >> 6;
  int lr = l & 15, g = l >> 4, lk = g * 8;
  int col0 = blockIdx.x * 16;
  int row0 = w * 32;
  f32x4 acc[2] = {};
#pragma unroll 4
  for (int k0 = 0; k0 < kF; k0 += 32) {
    bf16x8 a0 = *(const bf16x8*)&img_b[(row0 + lr) * kF + k0 + lk];
    bf16x8 a1 = *(const bf16x8*)&img_b[(row0 + 16 + lr) * kF + k0 + lk];
    bf16x8 b = *(const bf16x8*)&aw_b[(size_t)(col0 + lr) * kF + k0 + lk];
    acc[0] = MFMA(a0, b, acc[0]);
    acc[1] = MFMA(a1, b, acc[1]);
  }
  int col = col0 + lr;
  float bias = ab[col];
#pragma unroll
  for (int mf = 0; mf < 2; ++mf)
#pragma unroll
    for (int j = 0; j < 4; ++j) {
      int row = row0 + mf * 16 + g * 4 + j;
      float v = acc[mf][j] + bias;
      hf[row * kH + col] = v;
      hb[row * kH + col] = f2bf(v);
    }
}

// ---------------- GRU cell ----------------
// grid 64 (H/16 col tiles), 256 thr; wave w = rows 32w..32w+31
__global__ __launch_bounds__(256) void k_gru(
    const short* __restrict__ e_b, const short* __restrict__ hb_prev,
    const float* __restrict__ hf_prev,
    const short* __restrict__ wih_b, const short* __restrict__ whh_b,
    const float* __restrict__ bih, const float* __restrict__ bhh,
    float* __restrict__ hf_next, short* __restrict__ hb_next) {
  int tid = threadIdx.x;
  int l = tid & 63, w = tid >> 6;
  int lr = l & 15, g = l >> 4, lk = g * 8;
  int col0 = blockIdx.x * 16;
  int row0 = w * 32;
  f32x4 air[2] = {}, aiz[2] = {}, ain[2] = {};
  f32x4 ahr[2] = {}, ahz[2] = {}, ahn[2] = {};
#pragma unroll 4
  for (int k0 = 0; k0 < kE; k0 += 32) {
    bf16x8 a0 = *(const bf16x8*)&e_b[(row0 + lr) * kE + k0 + lk];
    bf16x8 a1 = *(const bf16x8*)&e_b[(row0 + 16 + lr) * kE + k0 + lk];
    bf16x8 br = *(const bf16x8*)&wih_b[(size_t)(col0 + lr) * kE + k0 + lk];
    bf16x8 bz = *(const bf16x8*)&wih_b[(size_t)(kH + col0 + lr) * kE + k0 + lk];
    bf16x8 bn = *(const bf16x8*)&wih_b[(size_t)(2 * kH + col0 + lr) * kE + k0 + lk];
    air[0] = MFMA(a0, br, air[0]); air[1] = MFMA(a1, br, air[1]);
    aiz[0] = MFMA(a0, bz, aiz[0]); aiz[1] = MFMA(a1, bz, aiz[1]);
    ain[0] = MFMA(a0, bn, ain[0]); ain[1] = MFMA(a1, bn, ain[1]);
  }
#pragma unroll 4
  for (int k0 = 0; k0 < kH; k0 += 32) {
    bf16x8 a0 = *(const bf16x8*)&hb_prev[(row0 + lr) * kH + k0 + lk];
    bf16x8 a1 = *(const bf16x8*)&hb_prev[(row0 + 16 + lr) * kH + k0 + lk];
    bf16x8 br = *(const bf16x8*)&whh_b[(size_t)(col0 + lr) * kH + k0 + lk];
    bf16x8 bz = *(const bf16x8*)&whh_b[(size_t)(kH + col0 + lr) * kH + k0 + lk];
    bf16x8 bn = *(const bf16x8*)&whh_b[(size_t)(2 * kH + col0 + lr) * kH + k0 + lk];
    ahr[0] = MFMA(a0, br, ahr[0]); ahr[1] = MFMA(a1, br, ahr[1]);
    ahz[0] = MFMA(a0, bz, ahz[0]); ahz[1] = MFMA(a1, bz, ahz[1]);
    ahn[0] = MFMA(a0, bn, ahn[0]); ahn[1] = MFMA(a1, bn, ahn[1]);
  }
  int col = col0 + lr;
  float bihr = bih[col], bhhr = bhh[col];
  float bihz = bih[kH + col], bhhz = bhh[kH + col];
  float bihn = bih[2 * kH + col], bhhn = bhh[2 * kH + col];
#pragma unroll
  for (int mf = 0; mf < 2; ++mf)
#pragma unroll
    for (int j = 0; j < 4; ++j) {
      int row = row0 + mf * 16 + g * 4 + j;
      float r = sigm(air[mf][j] + ahr[mf][j] + bihr + bhhr);
      float z = sigm(aiz[mf][j] + ahz[mf][j] + bihz + bhhz);
      float nn = tanhf(ain[mf][j] + bihn + r * (ahn[mf][j] + bhhn));
      float hv = (1.0f - z) * nn + z * hf_prev[row * kH + col];
      hf_next[row * kH + col] = hv;
      hb_next[row * kH + col] = f2bf(hv);
    }
}

// ---------------- logits GEMM (into out slice) + per-block softmax stats ----------------
// grid 256 (V/64 tiles), 256 thr; wave w owns ALL 128 rows x 16 cols (col-split waves)
// -> all waves load identical A fragments (L1 broadcast), 8-deep MFMA ILP.
__global__ __launch_bounds__(256) void k_logits(
    const short* __restrict__ h_b, const short* __restrict__ wout_b,
    const float* __restrict__ bout, const float* __restrict__ gum_t,
    float* __restrict__ outp, float* __restrict__ smax, float* __restrict__ ssum) {
  int tid = threadIdx.x;
  int l = tid & 63, w = tid >> 6;
  int lr = l & 15, g = l >> 4, lk = g * 8;
  int nc0 = blockIdx.x * 64 + w * 16;
  f32x4 acc[8] = {};
#pragma unroll 2
  for (int k0 = 0; k0 < kH; k0 += 32) {
    bf16x8 b = *(const bf16x8*)&wout_b[(size_t)(nc0 + lr) * kH + k0 + lk];
#pragma unroll
    for (int mf = 0; mf < 8; ++mf) {
      bf16x8 a = *(const bf16x8*)&h_b[(mf * 16 + lr) * kH + k0 + lk];
      acc[mf] = MFMA(a, b, acc[mf]);
    }
  }
  __shared__ float wmax[4][128];
  __shared__ float wsum[4][128];
  float bo = bout[nc0 + lr];
#pragma unroll
  for (int mf = 0; mf < 8; ++mf)
#pragma unroll
    for (int j = 0; j < 4; ++j) {
      int row = mf * 16 + g * 4 + j;
      float v = acc[mf][j] + bo + gum_t[(size_t)row * kV + nc0 + lr];
      outp[(size_t)row * (kT * kV) + nc0 + lr] = v;
      acc[mf][j] = v;
      float m = v;
#pragma unroll
      for (int s = 1; s < 16; s <<= 1) m = fmaxf(m, __shfl_xor(m, s, 64));
      if (lr == 0) wmax[w][row] = m;
    }
  __syncthreads();
#pragma unroll
  for (int mf = 0; mf < 8; ++mf)
#pragma unroll
    for (int j = 0; j < 4; ++j) {
      int row = mf * 16 + g * 4 + j;
      float bm = fmaxf(fmaxf(wmax[0][row], wmax[1][row]),
                       fmaxf(wmax[2][row], wmax[3][row]));
      float s = __expf(acc[mf][j] - bm);
#pragma unroll
      for (int sf = 1; sf < 16; sf <<= 1) s += __shfl_xor(s, sf, 64);
      if (lr == 0) wsum[w][row] = s;
    }
  __syncthreads();
  if (tid < 128) {
    int row = tid;
    float bm = fmaxf(fmaxf(wmax[0][row], wmax[1][row]),
                     fmaxf(wmax[2][row], wmax[3][row]));
    float s = wsum[0][row] + wsum[1][row] + wsum[2][row] + wsum[3][row];
    smax[(size_t)row * 256 + blockIdx.x] = bm;
    ssum[(size_t)row * 256 + blockIdx.x] = s;
  }
}

// ---------------- softmax finalize: x = exp(l - M)/D in-place on out slice + bf16 x ----------------
// grid 512 = 128 rows x 4 col-quarters; 256 thr
__global__ __launch_bounds__(256) void k_x(
    const float* __restrict__ smax, const float* __restrict__ ssum,
    float* __restrict__ outp, short* __restrict__ x_b) {
  int tid = threadIdx.x;
  int row = blockIdx.x >> 2;
  int q = blockIdx.x & 3;
  int l = tid & 63, w = tid >> 6;
  float mi = smax[row * 256 + tid];
  float si = ssum[row * 256 + tid];
  __shared__ float red[4];
  float m = mi;
#pragma unroll
  for (int s = 1; s < 64; s <<= 1) m = fmaxf(m, __shfl_xor(m, s, 64));
  if (l == 0) red[w] = m;
  __syncthreads();
  m = fmaxf(fmaxf(red[0], red[1]), fmaxf(red[2], red[3]));
  float d = si * __expf(mi - m);
#pragma unroll
  for (int s = 1; s < 64; s <<= 1) d += __shfl_xor(d, s, 64);
  __syncthreads();
  if (l == 0) red[w] = d;
  __syncthreads();
  float rd = 1.0f / (red[0] + red[1] + red[2] + red[3]);
  size_t rbase = (size_t)row * (kT * kV);
  int c0 = q * 4096 + tid * 4;
#pragma unroll
  for (int it = 0; it < 4; ++it) {
    int c = c0 + it * 1024;
    float4 lv = *(float4*)&outp[rbase + c];
    float4 xv;
    xv.x = __expf(lv.x - m) * rd;
    xv.y = __expf(lv.y - m) * rd;
    xv.z = __expf(lv.z - m) * rd;
    xv.w = __expf(lv.w - m) * rd;
    *(float4*)&outp[rbase + c] = xv;
    short4 xb;
    xb.x = f2bf(xv.x); xb.y = f2bf(xv.y); xb.z = f2bf(xv.z); xb.w = f2bf(xv.w);
    *(short4*)&x_b[(size_t)row * kV + c] = xb;
  }
}

// ---------------- e-partials: epart[kc] = x[:, kc-chunk] @ emb[:, kc-chunk].T ----------------
// grid 128 = (kc 32 K-chunks of 512) x (et 4 E-tiles of 128); 512 thr (8 waves 2x4)
__global__ __launch_bounds__(512) void k_e(
    const short* __restrict__ x_b, const short* __restrict__ emb_b,
    float* __restrict__ epart) {
  int tid = threadIdx.x;
  int l = tid & 63, w = tid >> 6;
  int lr = l & 15, g = l >> 4, lk = g * 8;
  int kc = blockIdx.x >> 2, et = blockIdx.x & 3;
  int mrow0 = (w >> 2) * 64;
  int col0 = et * 128 + (w & 3) * 32;
  int kbase = kc * 512;
  f32x4 acc[4][2] = {};
#pragma unroll 2
  for (int k0 = 0; k0 < 512; k0 += 32) {
    bf16x8 a[4], b[2];
#pragma unroll
    for (int mf = 0; mf < 4; ++mf)
      a[mf] = *(const bf16x8*)&x_b[(size_t)(mrow0 + mf * 16 + lr) * kV + kbase + k0 + lk];
#pragma unroll
    for (int nf = 0; nf < 2; ++nf)
      b[nf] = *(const bf16x8*)&emb_b[(size_t)(col0 + nf * 16 + lr) * kV + kbase + k0 + lk];
#pragma unroll
    for (int mf = 0; mf < 4; ++mf)
#pragma unroll
      for (int nf = 0; nf < 2; ++nf) acc[mf][nf] = MFMA(a[mf], b[nf], acc[mf][nf]);
  }
#pragma unroll
  for (int mf = 0; mf < 4; ++mf)
#pragma unroll
    for (int nf = 0; nf < 2; ++nf)
#pragma unroll
      for (int j = 0; j < 4; ++j) {
        int row = mrow0 + mf * 16 + g * 4 + j;
        int col = col0 + nf * 16 + lr;
        epart[((size_t)kc * kB + row) * kE + col] = acc[mf][nf][j];
      }
}

// ---------------- e = sum of 32 partials -> bf16 ----------------
// grid 256, 256 thr: one element each
__global__ __launch_bounds__(256) void k_ereduce(const float* __restrict__ epart,
                                                 short* __restrict__ e_b) {
  int i = blockIdx.x * 256 + threadIdx.x;   // 65536 elements
  float s = 0.0f;
#pragma unroll
  for (int k = 0; k < 32; ++k) s += epart[(size_t)k * (kB * kE) + i];
  e_b[i] = f2bf(s);
}

}  // namespace

extern "C" void kernel_launch(void* const* d_in, const int* in_sizes, int n_in,
                              void* d_out, int out_size, void* d_ws, size_t ws_size,
                              hipStream_t stream) {
  const float* img = (const float*)d_in[0];
  const float* aw = (const float*)d_in[1];
  const float* ab = (const float*)d_in[2];
  const float* wih = (const float*)d_in[3];
  const float* whh = (const float*)d_in[4];
  const float* bih = (const float*)d_in[5];
  const float* bhh = (const float*)d_in[6];
  const float* wout = (const float*)d_in[7];
  const float* bout = (const float*)d_in[8];
  const float* emb = (const float*)d_in[9];
  const float* sos = (const float*)d_in[10];
  const float* gum = (const float*)d_in[11];
  float* out = (float*)d_out;
  char* ws = (char*)d_ws;

  short* wout_b = (short*)(ws + 0);            // 33554432
  short* emb_b = (short*)(ws + 33554432);      // 16777216
  short* wih_b = (short*)(ws + 50331648);      // 3145728
  short* whh_b = (short*)(ws + 53477376);      // 6291456
  short* aw_b = (short*)(ws + 59768832);       // 4194304
  short* img_b = (short*)(ws + 63963136);      // 524288
  float* hf0 = (float*)(ws + 64487424);        // 524288
  float* hf1 = (float*)(ws + 65011712);        // 524288
  short* hb0 = (short*)(ws + 65536000);        // 262144
  short* hb1 = (short*)(ws + 65798144);        // 262144
  short* e_b = (short*)(ws + 66060288);        // 131072
  short* x_b = (short*)(ws + 66191360);        // 4194304
  float* smax = (float*)(ws + 70385664);       // 131072
  float* ssum = (float*)(ws + 70516736);       // 131072
  float* epart = (float*)(ws + 70647808);      // 8388608  (end 79036416 = R1 footprint)

  float* hf[2] = {hf0, hf1};
  short* hb[2] = {hb0, hb1};

  k_convert<<<2048, 256, 0, stream>>>(wout, emb, wih, whh, aw, img, sos, wout_b, emb_b,
                                      wih_b, whh_b, aw_b, img_b, e_b);
  k_h0<<<64, 256, 0, stream>>>(img_b, aw_b, ab, hf[0], hb[0]);
  for (int t = 0; t < kT; ++t) {
    int rp = t & 1, wp = rp ^ 1;
    float* outp = out + (size_t)t * kV;
    k_gru<<<64, 256, 0, stream>>>(e_b, hb[rp], hf[rp], wih_b, whh_b, bih, bhh, hf[wp],
                                  hb[wp]);
    k_logits<<<256, 256, 0, stream>>>(hb[wp], wout_b, bout, gum + (size_t)t * kB * kV,
                                      outp, smax, ssum);
    k_x<<<512, 256, 0, stream>>>(smax, ssum, outp, x_b);
    k_e<<<128, 512, 0, stream>>>(x_b, emb_b, epart);
    k_ereduce<<<256, 256, 0, stream>>>(epart, e_b);
  }
}

// Round 3
// 2086.598 us; speedup vs baseline: 1.5412x; 1.4685x over previous
//
#include <hip/hip_runtime.h>
#include <hip/hip_bf16.h>
#include <math.h>

namespace {

constexpr int kB = 128, kF = 2048, kH = 1024, kE = 512, kV = 16384, kT = 20;

typedef __attribute__((ext_vector_type(4))) float f32x4;
typedef __attribute__((ext_vector_type(8))) short bf16x8;

#define MFMA(a, b, c) __builtin_amdgcn_mfma_f32_16x16x32_bf16((a), (b), (c), 0, 0, 0)

__device__ __forceinline__ short f2bf(float f) {
  union { float f; unsigned u; } un;
  un.f = f;
  unsigned x = un.u;
  x += 0x7fffu + ((x >> 16) & 1u);
  return (short)(x >> 16);
}

__device__ __forceinline__ float bf2f(short s) {
  union { unsigned u; float f; } un;
  un.u = ((unsigned)(unsigned short)s) << 16;
  return un.f;
}

__device__ __forceinline__ float sigm(float x) { return 1.0f / (1.0f + __expf(-x)); }

__device__ __forceinline__ void cvt4(const float* __restrict__ s, short* __restrict__ d,
                                     long n4, long gid, long gs) {
  for (long i = gid; i < n4; i += gs) {
    float4 v = ((const float4*)s)[i];
    short4 o;
    o.x = f2bf(v.x); o.y = f2bf(v.y); o.z = f2bf(v.z); o.w = f2bf(v.w);
    ((short4*)d)[i] = o;
  }
}

// ---------------- prologue: fp32 -> bf16 weight conversion + e0 ----------------
__global__ __launch_bounds__(256) void k_convert(
    const float* __restrict__ wout, const float* __restrict__ emb,
    const float* __restrict__ wih, const float* __restrict__ whh,
    const float* __restrict__ aw, const float* __restrict__ img,
    const float* __restrict__ sos,
    short* __restrict__ wout_b, short* __restrict__ emb_b,
    short* __restrict__ wih_b, short* __restrict__ whh_b,
    short* __restrict__ aw_b, short* __restrict__ img_b,
    short* __restrict__ e0_b) {
  long gid = (long)blockIdx.x * blockDim.x + threadIdx.x;
  long gs = (long)gridDim.x * blockDim.x;
  cvt4(wout, wout_b, (long)kV * kH / 4, gid, gs);
  cvt4(emb, emb_b, (long)kE * kV / 4, gid, gs);
  cvt4(wih, wih_b, (long)3 * kH * kE / 4, gid, gs);
  cvt4(whh, whh_b, (long)3 * kH * kH / 4, gid, gs);
  cvt4(aw, aw_b, (long)kH * kF / 4, gid, gs);
  cvt4(img, img_b, (long)kB * kF / 4, gid, gs);
  for (long i = gid; i < kB * kE; i += gs) e0_b[i] = f2bf(sos[i & (kE - 1)]);
}

// ---------------- h0 = img @ agent_w.T + agent_b ----------------
__global__ __launch_bounds__(256) void k_h0(const short* __restrict__ img_b,
                                            const short* __restrict__ aw_b,
                                            const float* __restrict__ ab,
                                            float* __restrict__ hf, short* __restrict__ hb) {
  int tid = threadIdx.x;
  int l = tid & 63, w = tid >> 6;
  int lr = l & 15, g = l >> 4, lk = g * 8;
  int col0 = blockIdx.x * 16;
  int row0 = w * 32;
  f32x4 acc[2] = {};
#pragma unroll 4
  for (int k0 = 0; k0 < kF; k0 += 32) {
    bf16x8 a0 = *(const bf16x8*)&img_b[(row0 + lr) * kF + k0 + lk];
    bf16x8 a1 = *(const bf16x8*)&img_b[(row0 + 16 + lr) * kF + k0 + lk];
    bf16x8 b = *(const bf16x8*)&aw_b[(size_t)(col0 + lr) * kF + k0 + lk];
    acc[0] = MFMA(a0, b, acc[0]);
    acc[1] = MFMA(a1, b, acc[1]);
  }
  int col = col0 + lr;
  float bias = ab[col];
#pragma unroll
  for (int mf = 0; mf < 2; ++mf)
#pragma unroll
    for (int j = 0; j < 4; ++j) {
      int row = row0 + mf * 16 + g * 4 + j;
      float v = acc[mf][j] + bias;
      hf[row * kH + col] = v;
      hb[row * kH + col] = f2bf(v);
    }
}

// ---------------- GRU cell ----------------
// grid 64 (H/16 col tiles), 256 thr; wave w = rows 32w..32w+31; hf updated in place
__global__ __launch_bounds__(256) void k_gru(
    const short* __restrict__ e_b, const short* __restrict__ hb_prev,
    float* __restrict__ hf,
    const short* __restrict__ wih_b, const short* __restrict__ whh_b,
    const float* __restrict__ bih, const float* __restrict__ bhh,
    short* __restrict__ hb_next) {
  int tid = threadIdx.x;
  int l = tid & 63, w = tid >> 6;
  int lr = l & 15, g = l >> 4, lk = g * 8;
  int col0 = blockIdx.x * 16;
  int row0 = w * 32;
  f32x4 air[2] = {}, aiz[2] = {}, ain[2] = {};
  f32x4 ahr[2] = {}, ahz[2] = {}, ahn[2] = {};
#pragma unroll 4
  for (int k0 = 0; k0 < kE; k0 += 32) {
    bf16x8 a0 = *(const bf16x8*)&e_b[(row0 + lr) * kE + k0 + lk];
    bf16x8 a1 = *(const bf16x8*)&e_b[(row0 + 16 + lr) * kE + k0 + lk];
    bf16x8 br = *(const bf16x8*)&wih_b[(size_t)(col0 + lr) * kE + k0 + lk];
    bf16x8 bz = *(const bf16x8*)&wih_b[(size_t)(kH + col0 + lr) * kE + k0 + lk];
    bf16x8 bn = *(const bf16x8*)&wih_b[(size_t)(2 * kH + col0 + lr) * kE + k0 + lk];
    air[0] = MFMA(a0, br, air[0]); air[1] = MFMA(a1, br, air[1]);
    aiz[0] = MFMA(a0, bz, aiz[0]); aiz[1] = MFMA(a1, bz, aiz[1]);
    ain[0] = MFMA(a0, bn, ain[0]); ain[1] = MFMA(a1, bn, ain[1]);
  }
#pragma unroll 4
  for (int k0 = 0; k0 < kH; k0 += 32) {
    bf16x8 a0 = *(const bf16x8*)&hb_prev[(row0 + lr) * kH + k0 + lk];
    bf16x8 a1 = *(const bf16x8*)&hb_prev[(row0 + 16 + lr) * kH + k0 + lk];
    bf16x8 br = *(const bf16x8*)&whh_b[(size_t)(col0 + lr) * kH + k0 + lk];
    bf16x8 bz = *(const bf16x8*)&whh_b[(size_t)(kH + col0 + lr) * kH + k0 + lk];
    bf16x8 bn = *(const bf16x8*)&whh_b[(size_t)(2 * kH + col0 + lr) * kH + k0 + lk];
    ahr[0] = MFMA(a0, br, ahr[0]); ahr[1] = MFMA(a1, br, ahr[1]);
    ahz[0] = MFMA(a0, bz, ahz[0]); ahz[1] = MFMA(a1, bz, ahz[1]);
    ahn[0] = MFMA(a0, bn, ahn[0]); ahn[1] = MFMA(a1, bn, ahn[1]);
  }
  int col = col0 + lr;
  float bihr = bih[col], bhhr = bhh[col];
  float bihz = bih[kH + col], bhhz = bhh[kH + col];
  float bihn = bih[2 * kH + col], bhhn = bhh[2 * kH + col];
#pragma unroll
  for (int mf = 0; mf < 2; ++mf)
#pragma unroll
    for (int j = 0; j < 4; ++j) {
      int row = row0 + mf * 16 + g * 4 + j;
      float r = sigm(air[mf][j] + ahr[mf][j] + bihr + bhhr);
      float z = sigm(aiz[mf][j] + ahz[mf][j] + bihz + bhhz);
      float nn = tanhf(ain[mf][j] + bihn + r * (ahn[mf][j] + bhhn));
      float hv = (1.0f - z) * nn + z * hf[row * kH + col];
      hf[row * kH + col] = hv;
      hb_next[row * kH + col] = f2bf(hv);
    }
}

// ---------------- logits GEMM + block-local softmax: p = exp(l - m_b) bf16 + stats --------
// grid 256 (V/64 tiles), 512 thr; waves 2M x 4N: wave = 64 rows x 16 cols.
// Gumbel prefetched to registers before the K loop (latency hidden under MFMA).
__global__ __launch_bounds__(512) void k_logits(
    const short* __restrict__ h_b, const short* __restrict__ wout_b,
    const float* __restrict__ bout, const float* __restrict__ gum_t,
    short* __restrict__ p_b, float* __restrict__ smax, float* __restrict__ ssum) {
  int tid = threadIdx.x;
  int l = tid & 63, w = tid >> 6;
  int lr = l & 15, g = l >> 4, lk = g * 8;
  int wm = w >> 2, wn = w & 3;
  int n0 = blockIdx.x * 64;
  int col = n0 + wn * 16 + lr;
  int row0 = wm * 64;
  // prefetch gumbel for this lane's 16 output elements
  float gum[16];
#pragma unroll
  for (int mf = 0; mf < 4; ++mf)
#pragma unroll
    for (int j = 0; j < 4; ++j)
      gum[mf * 4 + j] = gum_t[(size_t)(row0 + mf * 16 + g * 4 + j) * kV + col];
  float bo = bout[col];
  f32x4 acc[4] = {};
#pragma unroll 2
  for (int k0 = 0; k0 < kH; k0 += 32) {
    bf16x8 b = *(const bf16x8*)&wout_b[(size_t)col * kH + k0 + lk];
#pragma unroll
    for (int mf = 0; mf < 4; ++mf) {
      bf16x8 a = *(const bf16x8*)&h_b[(row0 + mf * 16 + lr) * kH + k0 + lk];
      acc[mf] = MFMA(a, b, acc[mf]);
    }
  }
  __shared__ float lm[2][4][64];
  __shared__ float ls[2][4][64];
  float v[16];
#pragma unroll
  for (int i = 0; i < 16; ++i) v[i] = acc[i >> 2][i & 3] + bo + gum[i];
  // per-wave row max over its 16 cols (lanes sharing g)
#pragma unroll
  for (int i = 0; i < 16; ++i) {
    float m = v[i];
#pragma unroll
    for (int s = 1; s < 16; s <<= 1) m = fmaxf(m, __shfl_xor(m, s, 64));
    if (lr == 0) lm[wm][wn][(i >> 2) * 16 + g * 4 + (i & 3)] = m;
  }
  __syncthreads();
  float p[16];
#pragma unroll
  for (int i = 0; i < 16; ++i) {
    int rl = (i >> 2) * 16 + g * 4 + (i & 3);
    float mb = fmaxf(fmaxf(lm[wm][0][rl], lm[wm][1][rl]),
                     fmaxf(lm[wm][2][rl], lm[wm][3][rl]));
    p[i] = __expf(v[i] - mb);
    float s = p[i];
#pragma unroll
    for (int sf = 1; sf < 16; sf <<= 1) s += __shfl_xor(s, sf, 64);
    if (lr == 0) ls[wm][wn][rl] = s;
  }
#pragma unroll
  for (int i = 0; i < 16; ++i) {
    int rl = (i >> 2) * 16 + g * 4 + (i & 3);
    p_b[(size_t)(row0 + rl) * kV + col] = f2bf(p[i]);
  }
  __syncthreads();
  if (tid < 128) {
    int row = tid, wmm = tid >> 6, rl = tid & 63;
    float mb = fmaxf(fmaxf(lm[wmm][0][rl], lm[wmm][1][rl]),
                     fmaxf(lm[wmm][2][rl], lm[wmm][3][rl]));
    float sb = ls[wmm][0][rl] + ls[wmm][1][rl] + ls[wmm][2][rl] + ls[wmm][3][rl];
    smax[(size_t)row * 256 + blockIdx.x] = mb;
    ssum[(size_t)row * 256 + blockIdx.x] = sb;
  }
}

// ---------------- per-row global stats -> scale[row][block] = exp(m_b - M)/D ----------------
// grid 32 x 256 thr: wave per row
__global__ __launch_bounds__(256) void k_scale(const float* __restrict__ smax,
                                               const float* __restrict__ ssum,
                                               float* __restrict__ scalep) {
  int tid = threadIdx.x;
  int w = tid >> 6, l = tid & 63;
  int row = blockIdx.x * 4 + w;
  float4 mb = *(const float4*)&smax[row * 256 + l * 4];
  float4 sb = *(const float4*)&ssum[row * 256 + l * 4];
  float m = fmaxf(fmaxf(mb.x, mb.y), fmaxf(mb.z, mb.w));
#pragma unroll
  for (int s = 1; s < 64; s <<= 1) m = fmaxf(m, __shfl_xor(m, s, 64));
  float e0 = __expf(mb.x - m), e1 = __expf(mb.y - m);
  float e2 = __expf(mb.z - m), e3 = __expf(mb.w - m);
  float d = sb.x * e0 + sb.y * e1 + sb.z * e2 + sb.w * e3;
#pragma unroll
  for (int s = 1; s < 64; s <<= 1) d += __shfl_xor(d, s, 64);
  float rd = 1.0f / d;
  float4 sc;
  sc.x = e0 * rd; sc.y = e1 * rd; sc.z = e2 * rd; sc.w = e3 * rd;
  *(float4*)&scalep[row * 256 + l * 4] = sc;
}

// ---------------- fused finalize + out-write + e-partial GEMM ----------------
// grid 256 = kc(32 K-chunks of 512) x et(8 E-tiles of 64); 512 thr, waves 2M x 4N.
// Stages x = p*scale into XOR-swizzled LDS (bf16); et==0 blocks write fp32 x to out.
__global__ __launch_bounds__(512) void k_e(
    const short* __restrict__ p_b, const float* __restrict__ scalep,
    const short* __restrict__ emb_b, float* __restrict__ outp,
    float* __restrict__ epart) {
  int tid = threadIdx.x;
  int l = tid & 63, w = tid >> 6;
  int lr = l & 15, g = l >> 4, lk = g * 8;
  int wm = w >> 2, wn = w & 3;
  int kc = blockIdx.x >> 3, et = blockIdx.x & 7;
  int kbase = kc * 512;
  int colB = et * 64 + wn * 16 + lr;
  __shared__ bf16x8 xs8[2048];  // 128 rows x 128 cols bf16, XOR-swizzled
  char* xs = (char*)xs8;
  int colg = tid & 15, rrow = tid >> 4;
  f32x4 acc[4] = {};
  for (int s = 0; s < 4; ++s) {
    if (s) __syncthreads();
#pragma unroll
    for (int rr = 0; rr < 4; ++rr) {
      int row = rr * 32 + rrow;
      int cb = s * 128 + colg * 8;
      bf16x8 p8 = *(const bf16x8*)&p_b[(size_t)row * kV + kbase + cb];
      float scl = scalep[row * 256 + kc * 8 + (cb >> 6)];
      float f[8];
#pragma unroll
      for (int i = 0; i < 8; ++i) f[i] = bf2f(p8[i]) * scl;
      if (et == 0) {
        float4 o0, o1;
        o0.x = f[0]; o0.y = f[1]; o0.z = f[2]; o0.w = f[3];
        o1.x = f[4]; o1.y = f[5]; o1.z = f[6]; o1.w = f[7];
        *(float4*)&outp[(size_t)row * (kT * kV) + kbase + cb] = o0;
        *(float4*)&outp[(size_t)row * (kT * kV) + kbase + cb + 4] = o1;
      }
      bf16x8 xv;
#pragma unroll
      for (int i = 0; i < 8; ++i) xv[i] = f2bf(f[i]);
      unsigned off = (unsigned)(row * 256 + colg * 16) ^ ((row & 7) << 4);
      *(bf16x8*)(xs + off) = xv;
    }
    __syncthreads();
#pragma unroll
    for (int kk = 0; kk < 4; ++kk) {
      bf16x8 b = *(const bf16x8*)&emb_b[(size_t)colB * kV + kbase + s * 128 + kk * 32 + lk];
#pragma unroll
      for (int mf = 0; mf < 4; ++mf) {
        int rowa = wm * 64 + mf * 16 + lr;
        unsigned off = (unsigned)(rowa * 256 + (kk * 32 + lk) * 2) ^ ((rowa & 7) << 4);
        bf16x8 a = *(const bf16x8*)(xs + off);
        acc[mf] = MFMA(a, b, acc[mf]);
      }
    }
  }
#pragma unroll
  for (int mf = 0; mf < 4; ++mf)
#pragma unroll
    for (int j = 0; j < 4; ++j) {
      int row = wm * 64 + mf * 16 + g * 4 + j;
      epart[((size_t)kc * kB + row) * kE + et * 64 + wn * 16 + lr] = acc[mf][j];
    }
}

// ---------------- e = sum of 32 partials -> bf16 ----------------
__global__ __launch_bounds__(256) void k_ereduce(const float* __restrict__ epart,
                                                 short* __restrict__ e_b) {
  int i = blockIdx.x * 256 + threadIdx.x;  // 65536 elements
  float s = 0.0f;
#pragma unroll
  for (int k = 0; k < 32; ++k) s += epart[(size_t)k * (kB * kE) + i];
  e_b[i] = f2bf(s);
}

}  // namespace

extern "C" void kernel_launch(void* const* d_in, const int* in_sizes, int n_in,
                              void* d_out, int out_size, void* d_ws, size_t ws_size,
                              hipStream_t stream) {
  const float* img = (const float*)d_in[0];
  const float* aw = (const float*)d_in[1];
  const float* ab = (const float*)d_in[2];
  const float* wih = (const float*)d_in[3];
  const float* whh = (const float*)d_in[4];
  const float* bih = (const float*)d_in[5];
  const float* bhh = (const float*)d_in[6];
  const float* wout = (const float*)d_in[7];
  const float* bout = (const float*)d_in[8];
  const float* emb = (const float*)d_in[9];
  const float* sos = (const float*)d_in[10];
  const float* gum = (const float*)d_in[11];
  float* out = (float*)d_out;
  char* ws = (char*)d_ws;

  short* wout_b = (short*)(ws + 0);            // 33554432
  short* emb_b = (short*)(ws + 33554432);      // 16777216
  short* wih_b = (short*)(ws + 50331648);      // 3145728
  short* whh_b = (short*)(ws + 53477376);      // 6291456
  short* aw_b = (short*)(ws + 59768832);       // 4194304
  short* img_b = (short*)(ws + 63963136);      // 524288
  float* hf = (float*)(ws + 64487424);         // 524288 (in-place)
  short* hb0 = (short*)(ws + 65011712);        // 262144
  short* hb1 = (short*)(ws + 65273856);        // 262144
  short* e_b = (short*)(ws + 65536000);        // 131072
  short* p_b = (short*)(ws + 65667072);        // 4194304
  float* smax = (float*)(ws + 69861376);       // 131072
  float* ssum = (float*)(ws + 69992448);       // 131072
  float* scalep = (float*)(ws + 70123520);     // 131072
  float* epart = (float*)(ws + 70254592);      // 8388608 (end 78643200)

  short* hb[2] = {hb0, hb1};

  k_convert<<<2048, 256, 0, stream>>>(wout, emb, wih, whh, aw, img, sos, wout_b, emb_b,
                                      wih_b, whh_b, aw_b, img_b, e_b);
  k_h0<<<64, 256, 0, stream>>>(img_b, aw_b, ab, hf, hb[0]);
  for (int t = 0; t < kT; ++t) {
    int rp = t & 1, wp = rp ^ 1;
    float* outp = out + (size_t)t * kV;
    k_gru<<<64, 256, 0, stream>>>(e_b, hb[rp], hf, wih_b, whh_b, bih, bhh, hb[wp]);
    k_logits<<<256, 512, 0, stream>>>(hb[wp], wout_b, bout, gum + (size_t)t * kB * kV,
                                      p_b, smax, ssum);
    k_scale<<<32, 256, 0, stream>>>(smax, ssum, scalep);
    k_e<<<256, 512, 0, stream>>>(p_b, scalep, emb_b, outp, epart);
    k_ereduce<<<256, 256, 0, stream>>>(epart, e_b);
  }
}

// Round 4
// 1936.822 us; speedup vs baseline: 1.6604x; 1.0773x over previous
//
#include <hip/hip_runtime.h>
#include <hip/hip_bf16.h>
#include <math.h>

namespace {

constexpr int kB = 128, kF = 2048, kH = 1024, kE = 512, kV = 16384, kT = 20;

typedef __attribute__((ext_vector_type(4))) float f32x4;
typedef __attribute__((ext_vector_type(8))) short bf16x8;

#define MFMA(a, b, c) __builtin_amdgcn_mfma_f32_16x16x32_bf16((a), (b), (c), 0, 0, 0)

__device__ __forceinline__ short f2bf(float f) {
  union { float f; unsigned u; } un;
  un.f = f;
  unsigned x = un.u;
  x += 0x7fffu + ((x >> 16) & 1u);
  return (short)(x >> 16);
}

__device__ __forceinline__ float bf2f(short s) {
  union { unsigned u; float f; } un;
  un.u = ((unsigned)(unsigned short)s) << 16;
  return un.f;
}

__device__ __forceinline__ float sigm(float x) { return 1.0f / (1.0f + __expf(-x)); }

__device__ __forceinline__ void cvt4(const float* __restrict__ s, short* __restrict__ d,
                                     long n4, long gid, long gs) {
  for (long i = gid; i < n4; i += gs) {
    float4 v = ((const float4*)s)[i];
    short4 o;
    o.x = f2bf(v.x); o.y = f2bf(v.y); o.z = f2bf(v.z); o.w = f2bf(v.w);
    ((short4*)d)[i] = o;
  }
}

// ---------------- prologue: fp32 -> bf16 weight conversion + e0 ----------------
__global__ __launch_bounds__(256) void k_convert(
    const float* __restrict__ wout, const float* __restrict__ emb,
    const float* __restrict__ wih, const float* __restrict__ whh,
    const float* __restrict__ aw, const float* __restrict__ img,
    const float* __restrict__ sos,
    short* __restrict__ wout_b, short* __restrict__ emb_b,
    short* __restrict__ wih_b, short* __restrict__ whh_b,
    short* __restrict__ aw_b, short* __restrict__ img_b,
    short* __restrict__ e0_b) {
  long gid = (long)blockIdx.x * blockDim.x + threadIdx.x;
  long gs = (long)gridDim.x * blockDim.x;
  cvt4(wout, wout_b, (long)kV * kH / 4, gid, gs);
  cvt4(emb, emb_b, (long)kE * kV / 4, gid, gs);
  cvt4(wih, wih_b, (long)3 * kH * kE / 4, gid, gs);
  cvt4(whh, whh_b, (long)3 * kH * kH / 4, gid, gs);
  cvt4(aw, aw_b, (long)kH * kF / 4, gid, gs);
  cvt4(img, img_b, (long)kB * kF / 4, gid, gs);
  for (long i = gid; i < kB * kE; i += gs) e0_b[i] = f2bf(sos[i & (kE - 1)]);
}

// ---------------- h0 = img @ agent_w.T + agent_b ----------------
__global__ __launch_bounds__(256) void k_h0(const short* __restrict__ img_b,
                                            const short* __restrict__ aw_b,
                                            const float* __restrict__ ab,
                                            float* __restrict__ hf, short* __restrict__ hb) {
  int tid = threadIdx.x;
  int l = tid & 63, w = tid >> 6;
  int lr = l & 15, g = l >> 4, lk = g * 8;
  int col0 = blockIdx.x * 16;
  int row0 = w * 32;
  f32x4 acc[2] = {};
#pragma unroll 4
  for (int k0 = 0; k0 < kF; k0 += 32) {
    bf16x8 a0 = *(const bf16x8*)&img_b[(row0 + lr) * kF + k0 + lk];
    bf16x8 a1 = *(const bf16x8*)&img_b[(row0 + 16 + lr) * kF + k0 + lk];
    bf16x8 b = *(const bf16x8*)&aw_b[(size_t)(col0 + lr) * kF + k0 + lk];
    acc[0] = MFMA(a0, b, acc[0]);
    acc[1] = MFMA(a1, b, acc[1]);
  }
  int col = col0 + lr;
  float bias = ab[col];
#pragma unroll
  for (int mf = 0; mf < 2; ++mf)
#pragma unroll
    for (int j = 0; j < 4; ++j) {
      int row = row0 + mf * 16 + g * 4 + j;
      float v = acc[mf][j] + bias;
      hf[row * kH + col] = v;
      hb[row * kH + col] = f2bf(v);
    }
}

// ---------------- GRU cell ----------------
// grid 128 = 64 col-tiles x 2 row-halves; 256 thr; wave = 16 rows x 16 cols.
// B-loads identical across the 4 waves (L1 broadcast). Block 0 zeroes denom.
__global__ __launch_bounds__(256) void k_gru(
    const short* __restrict__ e_b, const short* __restrict__ hb_prev,
    float* __restrict__ hf,
    const short* __restrict__ wih_b, const short* __restrict__ whh_b,
    const float* __restrict__ bih, const float* __restrict__ bhh,
    short* __restrict__ hb_next, float* __restrict__ denom) {
  int tid = threadIdx.x;
  int l = tid & 63, w = tid >> 6;
  int lr = l & 15, g = l >> 4, lk = g * 8;
  int colt = blockIdx.x >> 1, half = blockIdx.x & 1;
  int col0 = colt * 16;
  int row0 = half * 64 + w * 16;
  if (blockIdx.x == 0 && tid < 32) {
    float4 z = {0.0f, 0.0f, 0.0f, 0.0f};
    *(float4*)&denom[tid * 4] = z;
  }
  f32x4 air = {}, aiz = {}, ain = {};
  f32x4 ahr = {}, ahz = {}, ahn = {};
#pragma unroll 8
  for (int k0 = 0; k0 < kE; k0 += 32) {
    bf16x8 a = *(const bf16x8*)&e_b[(row0 + lr) * kE + k0 + lk];
    bf16x8 br = *(const bf16x8*)&wih_b[(size_t)(col0 + lr) * kE + k0 + lk];
    bf16x8 bz = *(const bf16x8*)&wih_b[(size_t)(kH + col0 + lr) * kE + k0 + lk];
    bf16x8 bn = *(const bf16x8*)&wih_b[(size_t)(2 * kH + col0 + lr) * kE + k0 + lk];
    air = MFMA(a, br, air);
    aiz = MFMA(a, bz, aiz);
    ain = MFMA(a, bn, ain);
  }
#pragma unroll 8
  for (int k0 = 0; k0 < kH; k0 += 32) {
    bf16x8 a = *(const bf16x8*)&hb_prev[(row0 + lr) * kH + k0 + lk];
    bf16x8 br = *(const bf16x8*)&whh_b[(size_t)(col0 + lr) * kH + k0 + lk];
    bf16x8 bz = *(const bf16x8*)&whh_b[(size_t)(kH + col0 + lr) * kH + k0 + lk];
    bf16x8 bn = *(const bf16x8*)&whh_b[(size_t)(2 * kH + col0 + lr) * kH + k0 + lk];
    ahr = MFMA(a, br, ahr);
    ahz = MFMA(a, bz, ahz);
    ahn = MFMA(a, bn, ahn);
  }
  int col = col0 + lr;
  float bihr = bih[col], bhhr = bhh[col];
  float bihz = bih[kH + col], bhhz = bhh[kH + col];
  float bihn = bih[2 * kH + col], bhhn = bhh[2 * kH + col];
#pragma unroll
  for (int j = 0; j < 4; ++j) {
    int row = row0 + g * 4 + j;
    float r = sigm(air[j] + ahr[j] + bihr + bhhr);
    float z = sigm(aiz[j] + ahz[j] + bihz + bhhz);
    float nn = tanhf(ain[j] + bihn + r * (ahn[j] + bhhn));
    float hv = (1.0f - z) * nn + z * hf[row * kH + col];
    hf[row * kH + col] = hv;
    hb_next[row * kH + col] = f2bf(hv);
  }
}

// ---------------- logits GEMM + p = exp(logit+gumbel) + row-sum atomics ----------------
// grid 256 (V/64 tiles), 512 thr; waves 2M x 4N (wave 64r x 16c).
// No max subtraction: |logit+gumbel| << 88, exp() safe in fp32 (exact after division).
// Full-unrolled K-loop with register prefetch rings: B 8-deep, A 2-deep.
__global__ __launch_bounds__(512) void k_logits(
    const short* __restrict__ h_b, const short* __restrict__ wout_b,
    const float* __restrict__ bout, const float* __restrict__ gum_t,
    short* __restrict__ p_b, float* __restrict__ denom) {
  int tid = threadIdx.x;
  int l = tid & 63, w = tid >> 6;
  int lr = l & 15, g = l >> 4, lk = g * 8;
  int wm = w >> 2, wn = w & 3;
  int n0 = blockIdx.x * 64;
  int col = n0 + wn * 16 + lr;
  int row0 = wm * 64;
  // prefetch gumbel for this lane's 16 output elements
  float gum[16];
#pragma unroll
  for (int mf = 0; mf < 4; ++mf)
#pragma unroll
    for (int j = 0; j < 4; ++j)
      gum[mf * 4 + j] = gum_t[(size_t)(row0 + mf * 16 + g * 4 + j) * kV + col];
  float bo = bout[col];
  const short* Bp = &wout_b[(size_t)col * kH + lk];
  f32x4 acc[4] = {};
  bf16x8 brg[8], arg[2][4];
#pragma unroll
  for (int k = 0; k < 8; ++k) brg[k] = *(const bf16x8*)(Bp + k * 32);
#pragma unroll
  for (int k = 0; k < 2; ++k)
#pragma unroll
    for (int mf = 0; mf < 4; ++mf)
      arg[k][mf] = *(const bf16x8*)&h_b[(row0 + mf * 16 + lr) * kH + k * 32 + lk];
#pragma unroll
  for (int k = 0; k < 32; ++k) {
    acc[0] = MFMA(arg[k & 1][0], brg[k & 7], acc[0]);
    acc[1] = MFMA(arg[k & 1][1], brg[k & 7], acc[1]);
    acc[2] = MFMA(arg[k & 1][2], brg[k & 7], acc[2]);
    acc[3] = MFMA(arg[k & 1][3], brg[k & 7], acc[3]);
    if (k < 24) brg[k & 7] = *(const bf16x8*)(Bp + (k + 8) * 32);
    if (k < 30) {
#pragma unroll
      for (int mf = 0; mf < 4; ++mf)
        arg[k & 1][mf] =
            *(const bf16x8*)&h_b[(row0 + mf * 16 + lr) * kH + (k + 2) * 32 + lk];
    }
  }
  __shared__ float ls[2][4][64];
  float p[16];
#pragma unroll
  for (int i = 0; i < 16; ++i) p[i] = __expf(acc[i >> 2][i & 3] + bo + gum[i]);
#pragma unroll
  for (int i = 0; i < 16; ++i) {
    int rl = (i >> 2) * 16 + g * 4 + (i & 3);
    p_b[(size_t)(row0 + rl) * kV + col] = f2bf(p[i]);
  }
#pragma unroll
  for (int i = 0; i < 16; ++i) {
    float s = p[i];
#pragma unroll
    for (int sf = 1; sf < 16; sf <<= 1) s += __shfl_xor(s, sf, 64);
    if (lr == 0) ls[wm][wn][(i >> 2) * 16 + g * 4 + (i & 3)] = s;
  }
  __syncthreads();
  if (tid < 128) {
    int row = tid, wmm = tid >> 6, rl = tid & 63;
    float sb = ls[wmm][0][rl] + ls[wmm][1][rl] + ls[wmm][2][rl] + ls[wmm][3][rl];
    atomicAdd(&denom[row], sb);
  }
}

// ---------------- fused finalize + out-write + e-partial GEMM ----------------
// grid 256 = kc(32 K-chunks of 512) x et(8 E-tiles of 64); 512 thr, waves 2M x 4N.
// x = p * (1/denom[row]); stages x into XOR-swizzled LDS bf16; et==0 writes fp32 x to out.
__global__ __launch_bounds__(512) void k_e(
    const short* __restrict__ p_b, const float* __restrict__ denom,
    const short* __restrict__ emb_b, float* __restrict__ outp,
    float* __restrict__ epart) {
  int tid = threadIdx.x;
  int l = tid & 63, w = tid >> 6;
  int lr = l & 15, g = l >> 4, lk = g * 8;
  int wm = w >> 2, wn = w & 3;
  int kc = blockIdx.x >> 3, et = blockIdx.x & 7;
  int kbase = kc * 512;
  int colB = et * 64 + wn * 16 + lr;
  __shared__ float s_rd[kB];
  if (tid < kB) s_rd[tid] = 1.0f / denom[tid];
  __shared__ bf16x8 xs8[2048];  // 128 rows x 128 cols bf16, XOR-swizzled
  char* xs = (char*)xs8;
  int colg = tid & 15, rrow = tid >> 4;
  f32x4 acc[4] = {};
  __syncthreads();
  for (int s = 0; s < 4; ++s) {
    if (s) __syncthreads();
#pragma unroll
    for (int rr = 0; rr < 4; ++rr) {
      int row = rr * 32 + rrow;
      int cb = s * 128 + colg * 8;
      bf16x8 p8 = *(const bf16x8*)&p_b[(size_t)row * kV + kbase + cb];
      float scl = s_rd[row];
      float f[8];
#pragma unroll
      for (int i = 0; i < 8; ++i) f[i] = bf2f(p8[i]) * scl;
      if (et == 0) {
        float4 o0, o1;
        o0.x = f[0]; o0.y = f[1]; o0.z = f[2]; o0.w = f[3];
        o1.x = f[4]; o1.y = f[5]; o1.z = f[6]; o1.w = f[7];
        *(float4*)&outp[(size_t)row * (kT * kV) + kbase + cb] = o0;
        *(float4*)&outp[(size_t)row * (kT * kV) + kbase + cb + 4] = o1;
      }
      bf16x8 xv;
#pragma unroll
      for (int i = 0; i < 8; ++i) xv[i] = f2bf(f[i]);
      unsigned off = (unsigned)(row * 256 + colg * 16) ^ ((row & 7) << 4);
      *(bf16x8*)(xs + off) = xv;
    }
    __syncthreads();
#pragma unroll
    for (int kk = 0; kk < 4; ++kk) {
      bf16x8 b = *(const bf16x8*)&emb_b[(size_t)colB * kV + kbase + s * 128 + kk * 32 + lk];
#pragma unroll
      for (int mf = 0; mf < 4; ++mf) {
        int rowa = wm * 64 + mf * 16 + lr;
        unsigned off = (unsigned)(rowa * 256 + (kk * 32 + lk) * 2) ^ ((rowa & 7) << 4);
        bf16x8 a = *(const bf16x8*)(xs + off);
        acc[mf] = MFMA(a, b, acc[mf]);
      }
    }
  }
#pragma unroll
  for (int mf = 0; mf < 4; ++mf)
#pragma unroll
    for (int j = 0; j < 4; ++j) {
      int row = wm * 64 + mf * 16 + g * 4 + j;
      epart[((size_t)kc * kB + row) * kE + et * 64 + wn * 16 + lr] = acc[mf][j];
    }
}

// ---------------- e = sum of 32 partials -> bf16 ----------------
__global__ __launch_bounds__(256) void k_ereduce(const float* __restrict__ epart,
                                                 short* __restrict__ e_b) {
  int i = blockIdx.x * 256 + threadIdx.x;  // 65536 elements
  float s = 0.0f;
#pragma unroll
  for (int k = 0; k < 32; ++k) s += epart[(size_t)k * (kB * kE) + i];
  e_b[i] = f2bf(s);
}

}  // namespace

extern "C" void kernel_launch(void* const* d_in, const int* in_sizes, int n_in,
                              void* d_out, int out_size, void* d_ws, size_t ws_size,
                              hipStream_t stream) {
  const float* img = (const float*)d_in[0];
  const float* aw = (const float*)d_in[1];
  const float* ab = (const float*)d_in[2];
  const float* wih = (const float*)d_in[3];
  const float* whh = (const float*)d_in[4];
  const float* bih = (const float*)d_in[5];
  const float* bhh = (const float*)d_in[6];
  const float* wout = (const float*)d_in[7];
  const float* bout = (const float*)d_in[8];
  const float* emb = (const float*)d_in[9];
  const float* sos = (const float*)d_in[10];
  const float* gum = (const float*)d_in[11];
  float* out = (float*)d_out;
  char* ws = (char*)d_ws;

  short* wout_b = (short*)(ws + 0);            // 33554432
  short* emb_b = (short*)(ws + 33554432);      // 16777216
  short* wih_b = (short*)(ws + 50331648);      // 3145728
  short* whh_b = (short*)(ws + 53477376);      // 6291456
  short* aw_b = (short*)(ws + 59768832);       // 4194304
  short* img_b = (short*)(ws + 63963136);      // 524288
  float* hf = (float*)(ws + 64487424);         // 524288 (in-place fp32 h)
  short* hb0 = (short*)(ws + 65011712);        // 262144
  short* hb1 = (short*)(ws + 65273856);        // 262144
  short* e_b = (short*)(ws + 65536000);        // 131072
  short* p_b = (short*)(ws + 65667072);        // 4194304
  float* denom = (float*)(ws + 69861376);      // 4096 (128 used)
  float* epart = (float*)(ws + 69865472);      // 8388608 (end 78254080)

  short* hb[2] = {hb0, hb1};

  k_convert<<<2048, 256, 0, stream>>>(wout, emb, wih, whh, aw, img, sos, wout_b, emb_b,
                                      wih_b, whh_b, aw_b, img_b, e_b);
  k_h0<<<64, 256, 0, stream>>>(img_b, aw_b, ab, hf, hb[0]);
  for (int t = 0; t < kT; ++t) {
    int rp = t & 1, wp = rp ^ 1;
    float* outp = out + (size_t)t * kV;
    k_gru<<<128, 256, 0, stream>>>(e_b, hb[rp], hf, wih_b, whh_b, bih, bhh, hb[wp],
                                   denom);
    k_logits<<<256, 512, 0, stream>>>(hb[wp], wout_b, bout, gum + (size_t)t * kB * kV,
                                      p_b, denom);
    k_e<<<256, 512, 0, stream>>>(p_b, denom, emb_b, outp, epart);
    k_ereduce<<<256, 256, 0, stream>>>(epart, e_b);
  }
}